// Round 1
// baseline (6054.229 us; speedup 1.0000x reference)
//
#include <hip/hip_runtime.h>
#include <cstdint>
#include <cstddef>

// Problem constants
#define L_ 4
#define B_ 4
#define S_ 1024
#define D_ 768
#define H_ 12
#define DH_ 64
#define F_ 3072
#define W_ 128
#define R_ 257      // 2W+1
#define RP_ 264     // padded row stride for qpk/kpq (bf16 elems)

using f32x4 = __attribute__((ext_vector_type(4))) float;
typedef __bf16 bf16x8 __attribute__((ext_vector_type(8)));

__device__ __forceinline__ float bf2f(ushort u) {
  union { uint32_t i; float f; } x; x.i = ((uint32_t)u) << 16; return x.f;
}
__device__ __forceinline__ ushort f2bf(float f) {
  union { float f; uint32_t i; } x; x.f = f;
  uint32_t r = x.i + 0x7FFFu + ((x.i >> 16) & 1u);
  return (ushort)(r >> 16);
}
__device__ __forceinline__ void unpack8(const ushort* p, float* o) {
  uint4 u = *(const uint4*)p;
  o[0] = bf2f((ushort)(u.x & 0xffffu)); o[1] = bf2f((ushort)(u.x >> 16));
  o[2] = bf2f((ushort)(u.y & 0xffffu)); o[3] = bf2f((ushort)(u.y >> 16));
  o[4] = bf2f((ushort)(u.z & 0xffffu)); o[5] = bf2f((ushort)(u.z >> 16));
  o[6] = bf2f((ushort)(u.w & 0xffffu)); o[7] = bf2f((ushort)(u.w >> 16));
}

// ---------------------------------------------------------------------------
// Transpose + fp32->bf16 convert:  in (K,N) f32  ->  out (N,K) bf16
// ---------------------------------------------------------------------------
__global__ __launch_bounds__(256)
void transpose_cvt(const float* __restrict__ in, ushort* __restrict__ out,
                   int K, int N)
{
  __shared__ float tile[32][33];
  int n0 = blockIdx.x * 32, k0 = blockIdx.y * 32;
  int tx = threadIdx.x & 31, ty = threadIdx.x >> 5;   // 32 x 8
  #pragma unroll
  for (int r = 0; r < 32; r += 8)
    tile[ty + r][tx] = in[(size_t)(k0 + ty + r) * N + n0 + tx];
  __syncthreads();
  #pragma unroll
  for (int r = 0; r < 32; r += 8)
    out[(size_t)(n0 + ty + r) * K + k0 + tx] = f2bf(tile[tx][ty + r]);
}

// ---------------------------------------------------------------------------
// init: h = hidden_states (f32), hbf = bf16(h)
// ---------------------------------------------------------------------------
__global__ __launch_bounds__(256)
void init_h(const float* __restrict__ in, float* __restrict__ h,
            ushort* __restrict__ hbf, int n)
{
  int idx = blockIdx.x * 256 + threadIdx.x;
  if (idx < n) { float v = in[idx]; h[idx] = v; hbf[idx] = f2bf(v); }
}

__global__ __launch_bounds__(256)
void copy_out(const float* __restrict__ h, float* __restrict__ out, int n)
{
  int idx = blockIdx.x * 256 + threadIdx.x;
  if (idx < n) out[idx] = h[idx];
}

// ---------------------------------------------------------------------------
// MFMA GEMM:  C(M,N) = A(M,K) * Bt(N,K)^T,  A/Bt bf16, acc f32.
// 128x128 tile, BK=32, 4 waves (2x2), each wave a 64x64 sub-tile (4x4 frags
// of 16x16x32).  Epilogues:
//   EPI 0: out bf16 = acc                     (QKV)
//   EPI 1: out bf16 = gelu(acc + bias)        (W1)
//   EPI 2: resid f32 += acc + bias; also bf16 (WO)
//   EPI 3: resid f32 += acc + bias            (W2)
// M,N multiples of 128; K multiple of 32.
// ---------------------------------------------------------------------------
template<int EPI>
__global__ __launch_bounds__(256)
void gemm_bt(const ushort* __restrict__ A, const ushort* __restrict__ Bt,
             int M, int N, int K, const float* __restrict__ bias,
             float* __restrict__ resid, ushort* __restrict__ outbf)
{
  constexpr int KP = 56;  // padded LDS k-stride (bf16 elems), 112B rows
  __shared__ ushort Asm[128 * KP];
  __shared__ ushort Bsm[128 * KP];
  const int bm = blockIdx.x, bn = blockIdx.y;
  const int tid = threadIdx.x;
  const int lane = tid & 63, wave = tid >> 6;
  const int wm = wave >> 1, wn = wave & 1;
  const int srow = tid >> 2, scol = (tid & 3) * 8;
  const size_t rowA0 = (size_t)bm * 128, rowB0 = (size_t)bn * 128;
  const int fr = lane & 15;
  const int kb = (lane >> 4) * 8;

  f32x4 acc[4][4] = {};

  for (int k0 = 0; k0 < K; k0 += 32) {
    __syncthreads();
    #pragma unroll
    for (int it = 0; it < 2; ++it) {
      int r = srow + it * 64;
      *(uint4*)(&Asm[r * KP + scol]) =
          *(const uint4*)(A + (rowA0 + r) * K + k0 + scol);
      *(uint4*)(&Bsm[r * KP + scol]) =
          *(const uint4*)(Bt + (rowB0 + r) * K + k0 + scol);
    }
    __syncthreads();
    bf16x8 af[4], bfr[4];
    #pragma unroll
    for (int m = 0; m < 4; ++m)
      af[m] = *(const bf16x8*)(&Asm[(wm * 64 + m * 16 + fr) * KP + kb]);
    #pragma unroll
    for (int n = 0; n < 4; ++n)
      bfr[n] = *(const bf16x8*)(&Bsm[(wn * 64 + n * 16 + fr) * KP + kb]);
    #pragma unroll
    for (int m = 0; m < 4; ++m)
      #pragma unroll
      for (int n = 0; n < 4; ++n)
        acc[m][n] = __builtin_amdgcn_mfma_f32_16x16x32_bf16(
            af[m], bfr[n], acc[m][n], 0, 0, 0);
  }

  const int cr = (lane >> 4) * 4, cc = lane & 15;
  #pragma unroll
  for (int m = 0; m < 4; ++m) {
    #pragma unroll
    for (int n = 0; n < 4; ++n) {
      #pragma unroll
      for (int q = 0; q < 4; ++q) {
        size_t row = rowA0 + wm * 64 + m * 16 + cr + q;
        size_t col = rowB0 + wn * 64 + n * 16 + cc;
        float v = acc[m][n][q];
        if constexpr (EPI == 0) {
          outbf[row * N + col] = f2bf(v);
        } else if constexpr (EPI == 1) {
          float x = v + bias[col];
          float g = 0.5f * x * (1.0f + erff(x * 0.70710678118654752f));
          outbf[row * N + col] = f2bf(g);
        } else if constexpr (EPI == 2) {
          float x = v + bias[col] + resid[row * N + col];
          resid[row * N + col] = x;
          outbf[row * N + col] = f2bf(x);
        } else {
          float x = v + bias[col] + resid[row * N + col];
          resid[row * N + col] = x;
        }
      }
    }
  }
}

// ---------------------------------------------------------------------------
// pos GEMM:  out[b,h,i,r] = sum_d  X[b,i,h,d] * pos[h,d,r]
// X = q (coloff 0) or k (coloff 768) slice of qkv bf16 (4096 x 2304).
// pos: fp32 (H, DH, R) for this layer.  out: bf16 (B,H,S,RP_).
// Block: one (b,h) x 64 rows.  pos[h] staged to LDS as bf16.
// Lanes of a wave share r per iteration -> LDS broadcast reads.
// ---------------------------------------------------------------------------
__global__ __launch_bounds__(256)
void pos_gemm(const ushort* __restrict__ qkv, int coloff,
              const float* __restrict__ pos, ushort* __restrict__ out)
{
  __shared__ ushort plds[DH_ * RP_];
  int bh = blockIdx.x, sblk = blockIdx.y;
  int b = bh / H_, h = bh - b * H_;
  const float* ps = pos + (size_t)h * DH_ * R_;
  for (int idx = threadIdx.x; idx < DH_ * R_; idx += 256) {
    int d = idx / R_, r = idx - d * R_;
    plds[d * RP_ + r] = f2bf(ps[idx]);
  }
  __syncthreads();
  int il = threadIdx.x & 63, qt = threadIdx.x >> 6;
  int i = sblk * 64 + il;
  const ushort* qp = qkv + ((size_t)(b * S_ + i) * 2304 + coloff + h * 64);
  float q[64];
  #pragma unroll
  for (int c = 0; c < 8; ++c) unpack8(qp + c * 8, &q[c * 8]);
  int r0 = qt * 65;
  int r1 = (r0 + 65 > R_) ? R_ : r0 + 65;
  ushort* orow = out + ((size_t)((b * H_ + h) * S_ + i)) * RP_;
  for (int r = r0; r < r1; ++r) {
    float acc = 0.f;
    #pragma unroll
    for (int d = 0; d < 64; ++d) acc += q[d] * bf2f(plds[d * RP_ + r]);
    orow[r] = f2bf(acc);
  }
}

// ---------------------------------------------------------------------------
// Banded attention, one thread per (b,h,i), online softmax over the band.
// score(i,j) = q_i . k_j + qpk[i, j-i+W] + kpq[j, i-j+W]
// ctx written as bf16 into (B,S,H*DH) layout (attention output, pre-WO).
// ---------------------------------------------------------------------------
__global__ __launch_bounds__(256)
void attn_kernel(const ushort* __restrict__ qkv, const ushort* __restrict__ qpk,
                 const ushort* __restrict__ kpq, ushort* __restrict__ ctx)
{
  int t = blockIdx.x * 256 + threadIdx.x;       // < B*H*S
  int b = t / (H_ * S_);
  int rem = t - b * (H_ * S_);
  int h = rem >> 10;
  int i = rem & (S_ - 1);

  const ushort* qp = qkv + ((size_t)(b * S_ + i) * 2304 + h * 64);
  float q[64];
  #pragma unroll
  for (int c = 0; c < 8; ++c) unpack8(qp + c * 8, &q[c * 8]);

  const ushort* qpk_row = qpk + ((size_t)((b * H_ + h) * S_ + i)) * RP_;
  const ushort* kpq_base = kpq + ((size_t)(b * H_ + h)) * S_ * RP_;

  int jlo = (i - W_ < 0) ? 0 : i - W_;
  int jhi = (i + W_ > S_ - 1) ? S_ - 1 : i + W_;

  float m = -1e30f, lsum = 0.f;
  float cacc[64];
  #pragma unroll
  for (int d = 0; d < 64; ++d) cacc[d] = 0.f;

  for (int j = jlo; j <= jhi; ++j) {
    const ushort* kp = qkv + ((size_t)(b * S_ + j) * 2304 + 768 + h * 64);
    float s = 0.f;
    #pragma unroll
    for (int c = 0; c < 8; ++c) {
      float kv[8]; unpack8(kp + c * 8, kv);
      #pragma unroll
      for (int e = 0; e < 8; ++e) s += q[c * 8 + e] * kv[e];
    }
    s += bf2f(qpk_row[j - i + W_]);
    s += bf2f(kpq_base[(size_t)j * RP_ + (i - j + W_)]);

    float p;
    if (s > m) {
      float cf = __expf(m - s);   // first iter: exp(-huge) = 0
      m = s;
      lsum = lsum * cf + 1.f;
      p = 1.f;
      #pragma unroll
      for (int d = 0; d < 64; ++d) cacc[d] *= cf;
    } else {
      p = __expf(s - m);
      lsum += p;
    }
    const ushort* vp = kp + 768;
    #pragma unroll
    for (int c = 0; c < 8; ++c) {
      float vv[8]; unpack8(vp + c * 8, vv);
      #pragma unroll
      for (int e = 0; e < 8; ++e) cacc[c * 8 + e] += p * vv[e];
    }
  }
  float inv = 1.f / lsum;
  ushort* op = ctx + ((size_t)(b * S_ + i) * D_ + h * 64);
  #pragma unroll
  for (int d = 0; d < 64; ++d) op[d] = f2bf(cacc[d] * inv);
}

// ---------------------------------------------------------------------------
// LayerNorm over D=768, one row per block; writes h (f32) and hbf (bf16).
// ---------------------------------------------------------------------------
__global__ __launch_bounds__(256)
void ln_kernel(float* __restrict__ h, ushort* __restrict__ hbf,
               const float* __restrict__ g, const float* __restrict__ be)
{
  __shared__ float red[8];
  __shared__ float mv[2];
  int row = blockIdx.x, tid = threadIdx.x;
  float* hr = h + (size_t)row * D_;
  float v0 = hr[tid], v1 = hr[tid + 256], v2 = hr[tid + 512];
  float s = v0 + v1 + v2;
  float s2 = v0 * v0 + v1 * v1 + v2 * v2;
  #pragma unroll
  for (int o = 32; o >= 1; o >>= 1) {
    s += __shfl_xor(s, o, 64);
    s2 += __shfl_xor(s2, o, 64);
  }
  int wave = tid >> 6, lane = tid & 63;
  if (lane == 0) { red[wave] = s; red[4 + wave] = s2; }
  __syncthreads();
  if (tid == 0) {
    float ts = red[0] + red[1] + red[2] + red[3];
    float t2 = red[4] + red[5] + red[6] + red[7];
    float mu = ts / (float)D_;
    float var = t2 / (float)D_ - mu * mu;
    mv[0] = mu; mv[1] = rsqrtf(var + 1e-8f);
  }
  __syncthreads();
  float mu = mv[0], rstd = mv[1];
  #pragma unroll
  for (int c = 0; c < 3; ++c) {
    int col = tid + c * 256;
    float v = (c == 0) ? v0 : (c == 1) ? v1 : v2;
    float x = (v - mu) * rstd * g[col] + be[col];
    hr[col] = x;
    hbf[(size_t)row * D_ + col] = f2bf(x);
  }
}

// ---------------------------------------------------------------------------
extern "C" void kernel_launch(void* const* d_in, const int* in_sizes, int n_in,
                              void* d_out, int out_size, void* d_ws, size_t ws_size,
                              hipStream_t stream)
{
  const float* hidden = (const float*)d_in[0];
  // d_in[1] workspace_states unused; d_in[2] attention_mask all-ones (band only)
  const float* wq  = (const float*)d_in[3];
  const float* wk  = (const float*)d_in[4];
  const float* wv  = (const float*)d_in[5];
  const float* pq  = (const float*)d_in[6];   // pos_q -> kpq
  const float* pk  = (const float*)d_in[7];   // pos_k -> qpk
  const float* wo  = (const float*)d_in[8];
  const float* bo  = (const float*)d_in[9];
  const float* w1  = (const float*)d_in[10];
  const float* b1  = (const float*)d_in[11];
  const float* w2  = (const float*)d_in[12];
  const float* b2  = (const float*)d_in[13];
  const float* lng = (const float*)d_in[14];
  const float* lnb = (const float*)d_in[15];
  float* out = (float*)d_out;

  char* ws = (char*)d_ws;
  size_t off = 0;
  auto alloc = [&](size_t bytes) {
    void* p = ws + off;
    off += (bytes + 255) & ~(size_t)255;
    return p;
  };
  const size_t NT = (size_t)B_ * S_;   // 4096 tokens
  ushort* wqkv_t = (ushort*)alloc((size_t)L_ * 2304 * 768 * 2);
  ushort* wo_t   = (ushort*)alloc((size_t)L_ * 768 * 768 * 2);
  ushort* w1_t   = (ushort*)alloc((size_t)L_ * 3072 * 768 * 2);
  ushort* w2_t   = (ushort*)alloc((size_t)L_ * 768 * 3072 * 2);
  float*  hbuf   = (float*) alloc(NT * D_ * 4);
  ushort* hbf    = (ushort*)alloc(NT * D_ * 2);
  ushort* qkv    = (ushort*)alloc(NT * 2304 * 2);
  ushort* qpk    = (ushort*)alloc((size_t)B_ * H_ * S_ * RP_ * 2);
  ushort* kpq    = (ushort*)alloc((size_t)B_ * H_ * S_ * RP_ * 2);
  ushort* ctx    = (ushort*)alloc(NT * D_ * 2);
  ushort* inter  = (ushort*)alloc(NT * F_ * 2);
  (void)ws_size; (void)in_sizes; (void)n_in; (void)out_size;

  // Weight transpose-convert (every call; weights restored by harness)
  for (int l = 0; l < L_; ++l) {
    const size_t dd = (size_t)768 * 768;
    transpose_cvt<<<dim3(24, 24), 256, 0, stream>>>(
        wq + l * dd, wqkv_t + (size_t)l * 2304 * 768, 768, 768);
    transpose_cvt<<<dim3(24, 24), 256, 0, stream>>>(
        wk + l * dd, wqkv_t + (size_t)l * 2304 * 768 + dd, 768, 768);
    transpose_cvt<<<dim3(24, 24), 256, 0, stream>>>(
        wv + l * dd, wqkv_t + (size_t)l * 2304 * 768 + 2 * dd, 768, 768);
    transpose_cvt<<<dim3(24, 24), 256, 0, stream>>>(
        wo + l * dd, wo_t + l * dd, 768, 768);
    transpose_cvt<<<dim3(96, 24), 256, 0, stream>>>(
        w1 + (size_t)l * 768 * 3072, w1_t + (size_t)l * 3072 * 768, 768, 3072);
    transpose_cvt<<<dim3(24, 96), 256, 0, stream>>>(
        w2 + (size_t)l * 3072 * 768, w2_t + (size_t)l * 768 * 3072, 3072, 768);
  }

  init_h<<<(int)((NT * D_ + 255) / 256), 256, 0, stream>>>(
      hidden, hbuf, hbf, (int)(NT * D_));

  for (int l = 0; l < L_; ++l) {
    // QKV: (4096 x 768) x (768 x 2304)
    gemm_bt<0><<<dim3(32, 18), 256, 0, stream>>>(
        hbf, wqkv_t + (size_t)l * 2304 * 768, 4096, 2304, 768,
        nullptr, nullptr, qkv);
    // qpk = q @ pos_k[l], kpq = k @ pos_q[l]
    pos_gemm<<<dim3(B_ * H_, S_ / 64), 256, 0, stream>>>(
        qkv, 0, pk + (size_t)l * H_ * DH_ * R_, qpk);
    pos_gemm<<<dim3(B_ * H_, S_ / 64), 256, 0, stream>>>(
        qkv, 768, pq + (size_t)l * H_ * DH_ * R_, kpq);
    // banded attention
    attn_kernel<<<(B_ * H_ * S_) / 256, 256, 0, stream>>>(qkv, qpk, kpq, ctx);
    // h += ctx @ wo + bo  (writes h f32 + hbf)
    gemm_bt<2><<<dim3(32, 6), 256, 0, stream>>>(
        ctx, wo_t + (size_t)l * 768 * 768, 4096, 768, 768,
        bo + l * 768, hbuf, hbf);
    // inter = gelu(h @ w1 + b1)
    gemm_bt<1><<<dim3(32, 24), 256, 0, stream>>>(
        hbf, w1_t + (size_t)l * 3072 * 768, 4096, 3072, 768,
        b1 + l * 3072, nullptr, inter);
    // h += inter @ w2 + b2
    gemm_bt<3><<<dim3(32, 6), 256, 0, stream>>>(
        inter, w2_t + (size_t)l * 768 * 3072, 4096, 768, 3072,
        b2 + l * 768, hbuf, nullptr);
    // LayerNorm -> h, hbf
    ln_kernel<<<4096, 256, 0, stream>>>(hbuf, hbf, lng + l * 768, lnb + l * 768);
  }

  copy_out<<<(int)((NT * D_ + 255) / 256), 256, 0, stream>>>(
      hbuf, out, (int)(NT * D_));
}

// Round 3
// 1271.425 us; speedup vs baseline: 4.7618x; 4.7618x over previous
//
#include <hip/hip_runtime.h>
#include <cstdint>
#include <cstddef>

// Problem constants
#define L_ 4
#define B_ 4
#define S_ 1024
#define D_ 768
#define H_ 12
#define DH_ 64
#define F_ 3072
#define W_ 128
#define R_ 257      // 2W+1
#define RP2_ 272    // padded row stride for qpk/kpq (bf16 elems)
#define PTR_ 384    // padded r-rows in posT (zero beyond 257)

using f32x4 = __attribute__((ext_vector_type(4))) float;
typedef __bf16 bf16x8 __attribute__((ext_vector_type(8)));

__device__ __forceinline__ float bf2f(ushort u) {
  union { uint32_t i; float f; } x; x.i = ((uint32_t)u) << 16; return x.f;
}
__device__ __forceinline__ ushort f2bf(float f) {
  union { float f; uint32_t i; } x; x.f = f;
  uint32_t r = x.i + 0x7FFFu + ((x.i >> 16) & 1u);
  return (ushort)(r >> 16);
}

// ---------------------------------------------------------------------------
// Transpose + fp32->bf16 convert:  in (K,N) f32  ->  out (N,K) bf16
// ---------------------------------------------------------------------------
__global__ __launch_bounds__(256)
void transpose_cvt(const float* __restrict__ in, ushort* __restrict__ out,
                   int K, int N)
{
  __shared__ float tile[32][33];
  int n0 = blockIdx.x * 32, k0 = blockIdx.y * 32;
  int tx = threadIdx.x & 31, ty = threadIdx.x >> 5;   // 32 x 8
  #pragma unroll
  for (int r = 0; r < 32; r += 8)
    tile[ty + r][tx] = in[(size_t)(k0 + ty + r) * N + n0 + tx];
  __syncthreads();
  #pragma unroll
  for (int r = 0; r < 32; r += 8)
    out[(size_t)(n0 + ty + r) * K + k0 + tx] = f2bf(tile[tx][ty + r]);
}

// ---------------------------------------------------------------------------
// pos table transpose: pos (L*H, 64, 257) f32 -> posT (L*H, 384, 64) bf16,
// rows r >= 257 zeroed.
// ---------------------------------------------------------------------------
__global__ __launch_bounds__(256)
void pos_transpose(const float* __restrict__ pos, ushort* __restrict__ posT)
{
  __shared__ float tile[32][33];
  int lh = blockIdx.x;        // 0..47
  int rt = blockIdx.y;        // 0..11 (r tile of 32; covers 384)
  int dt = blockIdx.z;        // 0..1  (d tile of 32)
  int tx = threadIdx.x & 31, ty = threadIdx.x >> 5;  // 32 x 8
  const float* src = pos + (size_t)lh * 64 * R_;
  #pragma unroll
  for (int rr = 0; rr < 32; rr += 8) {
    int d = dt * 32 + ty + rr, r = rt * 32 + tx;
    tile[ty + rr][tx] = (r < R_) ? src[(size_t)d * R_ + r] : 0.f;
  }
  __syncthreads();
  ushort* dst = posT + (size_t)lh * PTR_ * 64;
  #pragma unroll
  for (int rr = 0; rr < 32; rr += 8) {
    int r = rt * 32 + ty + rr, d = dt * 32 + tx;
    dst[(size_t)r * 64 + d] = f2bf(tile[tx][ty + rr]);
  }
}

// ---------------------------------------------------------------------------
__global__ __launch_bounds__(256)
void init_h(const float* __restrict__ in, float* __restrict__ h,
            ushort* __restrict__ hbf, int n)
{
  int idx = blockIdx.x * 256 + threadIdx.x;
  if (idx < n) { float v = in[idx]; h[idx] = v; hbf[idx] = f2bf(v); }
}

__global__ __launch_bounds__(256)
void copy_out(const float* __restrict__ h, float* __restrict__ out, int n)
{
  int idx = blockIdx.x * 256 + threadIdx.x;
  if (idx < n) out[idx] = h[idx];
}

// ---------------------------------------------------------------------------
// MFMA GEMM:  C(M,N) = A(M,K) * Bt(N,K)^T,  A/Bt bf16, acc f32.
// ---------------------------------------------------------------------------
template<int EPI>
__global__ __launch_bounds__(256)
void gemm_bt(const ushort* __restrict__ A, const ushort* __restrict__ Bt,
             int M, int N, int K, const float* __restrict__ bias,
             float* __restrict__ resid, ushort* __restrict__ outbf)
{
  constexpr int KP = 56;  // padded LDS k-stride (bf16 elems)
  __shared__ ushort Asm[128 * KP];
  __shared__ ushort Bsm[128 * KP];
  const int bm = blockIdx.x, bn = blockIdx.y;
  const int tid = threadIdx.x;
  const int lane = tid & 63, wave = tid >> 6;
  const int wm = wave >> 1, wn = wave & 1;
  const int srow = tid >> 2, scol = (tid & 3) * 8;
  const size_t rowA0 = (size_t)bm * 128, rowB0 = (size_t)bn * 128;
  const int fr = lane & 15;
  const int kb = (lane >> 4) * 8;

  f32x4 acc[4][4] = {};

  for (int k0 = 0; k0 < K; k0 += 32) {
    __syncthreads();
    #pragma unroll
    for (int it = 0; it < 2; ++it) {
      int r = srow + it * 64;
      *(uint4*)(&Asm[r * KP + scol]) =
          *(const uint4*)(A + (rowA0 + r) * K + k0 + scol);
      *(uint4*)(&Bsm[r * KP + scol]) =
          *(const uint4*)(Bt + (rowB0 + r) * K + k0 + scol);
    }
    __syncthreads();
    bf16x8 af[4], bfr[4];
    #pragma unroll
    for (int m = 0; m < 4; ++m)
      af[m] = *(const bf16x8*)(&Asm[(wm * 64 + m * 16 + fr) * KP + kb]);
    #pragma unroll
    for (int n = 0; n < 4; ++n)
      bfr[n] = *(const bf16x8*)(&Bsm[(wn * 64 + n * 16 + fr) * KP + kb]);
    #pragma unroll
    for (int m = 0; m < 4; ++m)
      #pragma unroll
      for (int n = 0; n < 4; ++n)
        acc[m][n] = __builtin_amdgcn_mfma_f32_16x16x32_bf16(
            af[m], bfr[n], acc[m][n], 0, 0, 0);
  }

  const int cr = (lane >> 4) * 4, cc = lane & 15;
  #pragma unroll
  for (int m = 0; m < 4; ++m) {
    #pragma unroll
    for (int n = 0; n < 4; ++n) {
      #pragma unroll
      for (int q = 0; q < 4; ++q) {
        size_t row = rowA0 + wm * 64 + m * 16 + cr + q;
        size_t col = rowB0 + wn * 64 + n * 16 + cc;
        float v = acc[m][n][q];
        if constexpr (EPI == 0) {
          outbf[row * N + col] = f2bf(v);
        } else if constexpr (EPI == 1) {
          float x = v + bias[col];
          float g = 0.5f * x * (1.0f + erff(x * 0.70710678118654752f));
          outbf[row * N + col] = f2bf(g);
        } else if constexpr (EPI == 2) {
          float x = v + bias[col] + resid[row * N + col];
          resid[row * N + col] = x;
          outbf[row * N + col] = f2bf(x);
        } else {
          float x = v + bias[col] + resid[row * N + col];
          resid[row * N + col] = x;
        }
      }
    }
  }
}

// ---------------------------------------------------------------------------
// pos MFMA GEMM: out[(b,h,i), r] = sum_d X[b,i,h*64+d] * posT[h, r, d]
// X = q (which=0, ->qpk with posTk) or k slice (which=1, ->kpq with posTq)
// of qkv (4096 x 2304).  Grid: (32 M-tiles, 3 N-tiles(384), 24 = h*2+which).
// ---------------------------------------------------------------------------
__global__ __launch_bounds__(256)
void pos_mfma(const ushort* __restrict__ qkv,
              const ushort* __restrict__ posTq, const ushort* __restrict__ posTk,
              ushort* __restrict__ qpk, ushort* __restrict__ kpq)
{
  __shared__ ushort Asm[128 * 64];   // XOR-swizzled rows of 128B
  __shared__ ushort Bsm[128 * 64];
  const int bm = blockIdx.x, bn = blockIdx.y, z = blockIdx.z;
  const int h = z >> 1, which = z & 1;
  const ushort* A  = qkv + (which ? 768 : 0) + h * 64;
  const ushort* Bt = (which ? posTq : posTk) + (size_t)h * PTR_ * 64;
  ushort* out = which ? kpq : qpk;
  const int tid = threadIdx.x, lane = tid & 63, w = tid >> 6;
  const int wm = w >> 1, wn = w & 1;
  const int c = lane & 15, g = lane >> 4;

  #pragma unroll
  for (int it = 0; it < 4; ++it) {
    int row = (tid >> 3) + it * 32;
    int d0 = (tid & 7) * 8;
    uint4 av = *(const uint4*)(A + (size_t)(bm * 128 + row) * 2304 + d0);
    *(uint4*)((char*)Asm + row * 128 + ((d0 * 2) ^ ((row & 7) << 4))) = av;
    uint4 bv = *(const uint4*)(Bt + (size_t)(bn * 128 + row) * 64 + d0);
    *(uint4*)((char*)Bsm + row * 128 + ((d0 * 2) ^ ((row & 7) << 4))) = bv;
  }
  __syncthreads();

  f32x4 acc[4][4] = {};
  #pragma unroll
  for (int ks = 0; ks < 2; ++ks) {
    bf16x8 af[4], bfr[4];
    #pragma unroll
    for (int m = 0; m < 4; ++m) {
      int row = wm * 64 + m * 16 + c;
      af[m] = *(const bf16x8*)((const char*)Asm + row * 128 +
                               ((ks * 64 + g * 16) ^ ((row & 7) << 4)));
    }
    #pragma unroll
    for (int n = 0; n < 4; ++n) {
      int row = wn * 64 + n * 16 + c;
      bfr[n] = *(const bf16x8*)((const char*)Bsm + row * 128 +
                                ((ks * 64 + g * 16) ^ ((row & 7) << 4)));
    }
    #pragma unroll
    for (int m = 0; m < 4; ++m)
      #pragma unroll
      for (int n = 0; n < 4; ++n)
        acc[m][n] = __builtin_amdgcn_mfma_f32_16x16x32_bf16(
            af[m], bfr[n], acc[m][n], 0, 0, 0);
  }

  #pragma unroll
  for (int m = 0; m < 4; ++m) {
    #pragma unroll
    for (int n = 0; n < 4; ++n) {
      #pragma unroll
      for (int q = 0; q < 4; ++q) {
        int rowl = wm * 64 + m * 16 + g * 4 + q;
        int bi = bm * 128 + rowl;
        int b = bi >> 10, i = bi & 1023;
        int col = bn * 128 + wn * 64 + n * 16 + c;
        if (col < RP2_)
          out[((size_t)((b * H_ + h) * S_ + i)) * RP2_ + col] =
              f2bf(acc[m][n][q]);
      }
    }
  }
}

// ---------------------------------------------------------------------------
// Banded flash attention via MFMA. Block = (i-tile 64, b*h), 4 waves.
// Swapped QK^T (A=K, B=Q -> S^T[j,i]): per-lane softmax over j with 2 shfl.
// P -> per-wave LDS -> A-frags for PV with transposed-staged V.
// ---------------------------------------------------------------------------
__global__ __launch_bounds__(256)
void attn_mfma(const ushort* __restrict__ qkv,
               const ushort* __restrict__ qpk,  // (B*H*S, 272) bf16
               const ushort* __restrict__ kpq,
               ushort* __restrict__ ctx)        // (B*S, 768) bf16
{
  __shared__ ushort Qs[64 * 64];
  __shared__ ushort Ks[64 * 64];
  __shared__ ushort VTs[64 * 64];
  __shared__ ushort Ps[4][16 * 64];

  const int it0 = blockIdx.x;      // i-tile
  const int bh = blockIdx.y;
  const int b = bh / H_, h = bh - b * H_;
  const int i0 = it0 * 64;
  const int tid = threadIdx.x;
  const int lane = tid & 63, w = tid >> 6;
  const int c = lane & 15, g = lane >> 4;
  const size_t qkv_row0 = (size_t)(b * S_) * 2304;

  // stage Q (64 x 64), XOR-swizzled
  {
    int rr = tid >> 3, d0 = (tid & 7) * 8;
    #pragma unroll
    for (int it = 0; it < 2; ++it) {
      int row = rr + it * 32;
      uint4 v = *(const uint4*)(qkv + qkv_row0 + (size_t)(i0 + row) * 2304 +
                                h * 64 + d0);
      *(uint4*)((char*)Qs + row * 128 + ((d0 * 2) ^ ((row & 7) << 4))) = v;
    }
  }
  __syncthreads();

  // hoist Q B-fragments (col i = w*16 + c)
  bf16x8 qb[2];
  #pragma unroll
  for (int ks = 0; ks < 2; ++ks) {
    int row = w * 16 + c;
    qb[ks] = *(const bf16x8*)((const char*)Qs + row * 128 +
                              ((ks * 64 + g * 16) ^ ((row & 7) << 4)));
  }

  f32x4 acc[4] = {};
  float mrun = -1e30f, lrun = 0.f;
  const int i_mine = i0 + w * 16 + c;
  const ushort* qrow = qpk + ((size_t)(bh * S_) + i_mine) * RP2_;
  const ushort* kbase = kpq + (size_t)(bh * S_) * RP2_;

  for (int ccnk = 0; ccnk < 5; ++ccnk) {
    int jb = i0 - 128 + 64 * ccnk;
    if (jb < 0 || jb >= S_) continue;
    __syncthreads();
    // stage K chunk + transposed V chunk
    {
      int rr = tid >> 3, d0 = (tid & 7) * 8;
      #pragma unroll
      for (int it = 0; it < 2; ++it) {
        int row = rr + it * 32;
        const ushort* src = qkv + qkv_row0 + (size_t)(jb + row) * 2304 +
                            768 + h * 64 + d0;
        uint4 kv = *(const uint4*)src;
        *(uint4*)((char*)Ks + row * 128 + ((d0 * 2) ^ ((row & 7) << 4))) = kv;
        uint4 vv = *(const uint4*)(src + 768);
        ushort tmp[8];
        *(uint4*)tmp = vv;
        #pragma unroll
        for (int e = 0; e < 8; ++e) {
          int e2 = (e + tid) & 7;            // rotate to spread banks
          int d = d0 + e2;
          *(ushort*)((char*)VTs + d * 128 + ((row * 2) ^ ((d & 7) << 4))) =
              tmp[e2];
        }
      }
    }
    __syncthreads();

    // QK^T swapped: sc[f] holds S^T[j = 16f + 4g + q][i = w*16 + c]
    f32x4 sc[4];
    #pragma unroll
    for (int f = 0; f < 4; ++f) {
      f32x4 zz = {0.f, 0.f, 0.f, 0.f};
      #pragma unroll
      for (int ks = 0; ks < 2; ++ks) {
        int row = f * 16 + c;
        bf16x8 a = *(const bf16x8*)((const char*)Ks + row * 128 +
                                    ((ks * 64 + g * 16) ^ ((row & 7) << 4)));
        zz = __builtin_amdgcn_mfma_f32_16x16x32_bf16(a, qb[ks], zz, 0, 0, 0);
      }
      sc[f] = zz;
    }

    // bias + band mask
    float svals[16];
    #pragma unroll
    for (int f = 0; f < 4; ++f) {
      #pragma unroll
      for (int q = 0; q < 4; ++q) {
        int jl = f * 16 + g * 4 + q;
        int j = jb + jl;
        int dlt = j - i_mine;
        float s = sc[f][q];
        if (dlt >= -W_ && dlt <= W_) {
          s += bf2f(qrow[dlt + W_]);
          s += bf2f(kbase[(size_t)j * RP2_ + (W_ - dlt)]);
        } else {
          s = -1e30f;
        }
        svals[f * 4 + q] = s;
      }
    }

    // online softmax (per i: lanes c, c+16, c+32, c+48 share state)
    float cm = svals[0];
    #pragma unroll
    for (int q = 1; q < 16; ++q) cm = fmaxf(cm, svals[q]);
    cm = fmaxf(cm, __shfl_xor(cm, 16, 64));
    cm = fmaxf(cm, __shfl_xor(cm, 32, 64));
    float mnew = fmaxf(mrun, cm);
    float cf = __expf(mrun - mnew);
    float psum = 0.f;
    ushort pb[16];
    #pragma unroll
    for (int q = 0; q < 16; ++q) {
      float p = __expf(svals[q] - mnew);
      psum += p;
      pb[q] = f2bf(p);
    }
    psum += __shfl_xor(psum, 16, 64);
    psum += __shfl_xor(psum, 32, 64);
    lrun = lrun * cf + psum;
    mrun = mnew;

    // rescale ctx accumulator: acc rows i_local = g*4 + q need cf from lane i_local
    float cfr[4];
    #pragma unroll
    for (int q = 0; q < 4; ++q) cfr[q] = __shfl(cf, (g << 2) + q, 64);
    #pragma unroll
    for (int n = 0; n < 4; ++n)
      #pragma unroll
      for (int q = 0; q < 4; ++q) acc[n][q] *= cfr[q];

    // write P (bf16) to per-wave LDS in [i_local][jl] layout
    #pragma unroll
    for (int f = 0; f < 4; ++f) {
      uint2 p2;
      p2.x = (uint)pb[f * 4 + 0] | ((uint)pb[f * 4 + 1] << 16);
      p2.y = (uint)pb[f * 4 + 2] | ((uint)pb[f * 4 + 3] << 16);
      *(uint2*)((char*)&Ps[w][0] + c * 128 +
                ((f * 32 + g * 8) ^ ((c & 7) << 4))) = p2;
    }
    asm volatile("s_waitcnt lgkmcnt(0)" ::: "memory");

    // PV: acc[n] += P(16 x 64) * V(64 x d-frag n)
    #pragma unroll
    for (int ks = 0; ks < 2; ++ks) {
      bf16x8 pa = *(const bf16x8*)((const char*)&Ps[w][0] + c * 128 +
                                   ((ks * 64 + g * 16) ^ ((c & 7) << 4)));
      #pragma unroll
      for (int n = 0; n < 4; ++n) {
        int dd = n * 16 + c;
        bf16x8 bv = *(const bf16x8*)((const char*)VTs + dd * 128 +
                                     ((ks * 64 + g * 16) ^ ((dd & 7) << 4)));
        acc[n] = __builtin_amdgcn_mfma_f32_16x16x32_bf16(pa, bv, acc[n], 0, 0, 0);
      }
    }
  }

  // normalize + store ctx
  float inv = 1.0f / lrun;
  float invr[4];
  #pragma unroll
  for (int q = 0; q < 4; ++q) invr[q] = __shfl(inv, (g << 2) + q, 64);
  #pragma unroll
  for (int n = 0; n < 4; ++n) {
    #pragma unroll
    for (int q = 0; q < 4; ++q) {
      int i_g = i0 + w * 16 + g * 4 + q;
      int d = n * 16 + c;
      ctx[((size_t)(b * S_ + i_g)) * D_ + h * 64 + d] = f2bf(acc[n][q] * invr[q]);
    }
  }
}

// ---------------------------------------------------------------------------
// LayerNorm over D=768
// ---------------------------------------------------------------------------
__global__ __launch_bounds__(256)
void ln_kernel(float* __restrict__ h, ushort* __restrict__ hbf,
               const float* __restrict__ g, const float* __restrict__ be)
{
  __shared__ float red[8];
  __shared__ float mv[2];
  int row = blockIdx.x, tid = threadIdx.x;
  float* hr = h + (size_t)row * D_;
  float v0 = hr[tid], v1 = hr[tid + 256], v2 = hr[tid + 512];
  float s = v0 + v1 + v2;
  float s2 = v0 * v0 + v1 * v1 + v2 * v2;
  #pragma unroll
  for (int o = 32; o >= 1; o >>= 1) {
    s += __shfl_xor(s, o, 64);
    s2 += __shfl_xor(s2, o, 64);
  }
  int wave = tid >> 6, lane = tid & 63;
  if (lane == 0) { red[wave] = s; red[4 + wave] = s2; }
  __syncthreads();
  if (tid == 0) {
    float ts = red[0] + red[1] + red[2] + red[3];
    float t2 = red[4] + red[5] + red[6] + red[7];
    float mu = ts / (float)D_;
    float var = t2 / (float)D_ - mu * mu;
    mv[0] = mu; mv[1] = rsqrtf(var + 1e-8f);
  }
  __syncthreads();
  float mu = mv[0], rstd = mv[1];
  #pragma unroll
  for (int cidx = 0; cidx < 3; ++cidx) {
    int col = tid + cidx * 256;
    float v = (cidx == 0) ? v0 : (cidx == 1) ? v1 : v2;
    float x = (v - mu) * rstd * g[col] + be[col];
    hr[col] = x;
    hbf[(size_t)row * D_ + col] = f2bf(x);
  }
}

// ---------------------------------------------------------------------------
extern "C" void kernel_launch(void* const* d_in, const int* in_sizes, int n_in,
                              void* d_out, int out_size, void* d_ws, size_t ws_size,
                              hipStream_t stream)
{
  const float* hidden = (const float*)d_in[0];
  const float* wq  = (const float*)d_in[3];
  const float* wk  = (const float*)d_in[4];
  const float* wv  = (const float*)d_in[5];
  const float* pq  = (const float*)d_in[6];   // pos_q -> kpq
  const float* pk  = (const float*)d_in[7];   // pos_k -> qpk
  const float* wo  = (const float*)d_in[8];
  const float* bo  = (const float*)d_in[9];
  const float* w1  = (const float*)d_in[10];
  const float* b1  = (const float*)d_in[11];
  const float* w2  = (const float*)d_in[12];
  const float* b2  = (const float*)d_in[13];
  const float* lng = (const float*)d_in[14];
  const float* lnb = (const float*)d_in[15];
  float* out = (float*)d_out;

  char* ws = (char*)d_ws;
  size_t off = 0;
  auto alloc = [&](size_t bytes) {
    void* p = ws + off;
    off += (bytes + 255) & ~(size_t)255;
    return p;
  };
  const size_t NT = (size_t)B_ * S_;   // 4096 tokens
  ushort* wqkv_t = (ushort*)alloc((size_t)L_ * 2304 * 768 * 2);
  ushort* wo_t   = (ushort*)alloc((size_t)L_ * 768 * 768 * 2);
  ushort* w1_t   = (ushort*)alloc((size_t)L_ * 3072 * 768 * 2);
  ushort* w2_t   = (ushort*)alloc((size_t)L_ * 768 * 3072 * 2);
  ushort* posTq  = (ushort*)alloc((size_t)L_ * H_ * PTR_ * 64 * 2);
  ushort* posTk  = (ushort*)alloc((size_t)L_ * H_ * PTR_ * 64 * 2);
  float*  hbuf   = (float*) alloc(NT * D_ * 4);
  ushort* hbf    = (ushort*)alloc(NT * D_ * 2);
  ushort* qkv    = (ushort*)alloc(NT * 2304 * 2);
  ushort* qpk    = (ushort*)alloc((size_t)B_ * H_ * S_ * RP2_ * 2);
  ushort* kpq    = (ushort*)alloc((size_t)B_ * H_ * S_ * RP2_ * 2);
  ushort* ctx    = (ushort*)alloc(NT * D_ * 2);
  ushort* inter  = (ushort*)alloc(NT * F_ * 2);
  (void)ws_size; (void)in_sizes; (void)n_in; (void)out_size;

  // Weight transpose-convert (every call; inputs restored by harness)
  for (int l = 0; l < L_; ++l) {
    const size_t dd = (size_t)768 * 768;
    transpose_cvt<<<dim3(24, 24), 256, 0, stream>>>(
        wq + l * dd, wqkv_t + (size_t)l * 2304 * 768, 768, 768);
    transpose_cvt<<<dim3(24, 24), 256, 0, stream>>>(
        wk + l * dd, wqkv_t + (size_t)l * 2304 * 768 + dd, 768, 768);
    transpose_cvt<<<dim3(24, 24), 256, 0, stream>>>(
        wv + l * dd, wqkv_t + (size_t)l * 2304 * 768 + 2 * dd, 768, 768);
    transpose_cvt<<<dim3(24, 24), 256, 0, stream>>>(
        wo + l * dd, wo_t + l * dd, 768, 768);
    transpose_cvt<<<dim3(96, 24), 256, 0, stream>>>(
        w1 + (size_t)l * 768 * 3072, w1_t + (size_t)l * 3072 * 768, 768, 3072);
    transpose_cvt<<<dim3(24, 96), 256, 0, stream>>>(
        w2 + (size_t)l * 3072 * 768, w2_t + (size_t)l * 768 * 3072, 3072, 768);
  }
  pos_transpose<<<dim3(48, 12, 2), 256, 0, stream>>>(pq, posTq);
  pos_transpose<<<dim3(48, 12, 2), 256, 0, stream>>>(pk, posTk);

  init_h<<<(int)((NT * D_ + 255) / 256), 256, 0, stream>>>(
      hidden, hbuf, hbf, (int)(NT * D_));

  for (int l = 0; l < L_; ++l) {
    gemm_bt<0><<<dim3(32, 18), 256, 0, stream>>>(
        hbf, wqkv_t + (size_t)l * 2304 * 768, 4096, 2304, 768,
        nullptr, nullptr, qkv);
    pos_mfma<<<dim3(32, 3, 24), 256, 0, stream>>>(
        qkv, posTq + (size_t)l * H_ * PTR_ * 64,
        posTk + (size_t)l * H_ * PTR_ * 64, qpk, kpq);
    attn_mfma<<<dim3(16, 48), 256, 0, stream>>>(qkv, qpk, kpq, ctx);
    gemm_bt<2><<<dim3(32, 6), 256, 0, stream>>>(
        ctx, wo_t + (size_t)l * 768 * 768, 4096, 768, 768,
        bo + l * 768, hbuf, hbf);
    gemm_bt<1><<<dim3(32, 24), 256, 0, stream>>>(
        hbf, w1_t + (size_t)l * 3072 * 768, 4096, 3072, 768,
        b1 + l * 3072, nullptr, inter);
    gemm_bt<3><<<dim3(32, 6), 256, 0, stream>>>(
        inter, w2_t + (size_t)l * 768 * 3072, 4096, 768, 3072,
        b2 + l * 768, hbuf, nullptr);
    ln_kernel<<<4096, 256, 0, stream>>>(hbuf, hbf, lng + l * 768, lnb + l * 768);
  }

  copy_out<<<(int)((NT * D_ + 255) / 256), 256, 0, stream>>>(
      hbuf, out, (int)(NT * D_));
}

// Round 6
// 1161.882 us; speedup vs baseline: 5.2107x; 1.0943x over previous
//
#include <hip/hip_runtime.h>
#include <cstdint>
#include <cstddef>

// Problem constants
#define L_ 4
#define B_ 4
#define S_ 1024
#define D_ 768
#define H_ 12
#define DH_ 64
#define F_ 3072
#define W_ 128
#define R_ 257      // 2W+1
#define RP2_ 272    // padded row stride for qpk/kpq (bf16 elems)
#define PTR_ 384    // padded r-rows in posT (zero beyond 257)

using f32x4 = __attribute__((ext_vector_type(4))) float;
typedef __bf16 bf16x8 __attribute__((ext_vector_type(8)));

#define AS1(p) ((const __attribute__((address_space(1))) void*)(p))
#define AS3(p) ((__attribute__((address_space(3))) void*)(p))

__device__ __forceinline__ float bf2f(ushort u) {
  union { uint32_t i; float f; } x; x.i = ((uint32_t)u) << 16; return x.f;
}
__device__ __forceinline__ ushort f2bf(float f) {
  union { float f; uint32_t i; } x; x.f = f;
  uint32_t r = x.i + 0x7FFFu + ((x.i >> 16) & 1u);
  return (ushort)(r >> 16);
}

// ---------------------------------------------------------------------------
// Transpose + fp32->bf16 convert:  in (K,N) f32  ->  out (N,K) bf16
// ---------------------------------------------------------------------------
__global__ __launch_bounds__(256)
void transpose_cvt(const float* __restrict__ in, ushort* __restrict__ out,
                   int K, int N)
{
  __shared__ float tile[32][33];
  int n0 = blockIdx.x * 32, k0 = blockIdx.y * 32;
  int tx = threadIdx.x & 31, ty = threadIdx.x >> 5;   // 32 x 8
  #pragma unroll
  for (int r = 0; r < 32; r += 8)
    tile[ty + r][tx] = in[(size_t)(k0 + ty + r) * N + n0 + tx];
  __syncthreads();
  #pragma unroll
  for (int r = 0; r < 32; r += 8)
    out[(size_t)(n0 + ty + r) * K + k0 + tx] = f2bf(tile[tx][ty + r]);
}

// ---------------------------------------------------------------------------
// pos table transpose: pos (L*H, 64, 257) f32 -> posT (L*H, 384, 64) bf16,
// rows r >= 257 zeroed.
// ---------------------------------------------------------------------------
__global__ __launch_bounds__(256)
void pos_transpose(const float* __restrict__ pos, ushort* __restrict__ posT)
{
  __shared__ float tile[32][33];
  int lh = blockIdx.x;        // 0..47
  int rt = blockIdx.y;        // 0..11 (r tile of 32; covers 384)
  int dt = blockIdx.z;        // 0..1  (d tile of 32)
  int tx = threadIdx.x & 31, ty = threadIdx.x >> 5;  // 32 x 8
  const float* src = pos + (size_t)lh * 64 * R_;
  #pragma unroll
  for (int rr = 0; rr < 32; rr += 8) {
    int d = dt * 32 + ty + rr, r = rt * 32 + tx;
    tile[ty + rr][tx] = (r < R_) ? src[(size_t)d * R_ + r] : 0.f;
  }
  __syncthreads();
  ushort* dst = posT + (size_t)lh * PTR_ * 64;
  #pragma unroll
  for (int rr = 0; rr < 32; rr += 8) {
    int r = rt * 32 + ty + rr, d = dt * 32 + tx;
    dst[(size_t)r * 64 + d] = f2bf(tile[tx][ty + rr]);
  }
}

// ---------------------------------------------------------------------------
__global__ __launch_bounds__(256)
void init_h(const float* __restrict__ in, float* __restrict__ h,
            ushort* __restrict__ hbf, int n)
{
  int idx = blockIdx.x * 256 + threadIdx.x;
  if (idx < n) { float v = in[idx]; h[idx] = v; hbf[idx] = f2bf(v); }
}

__global__ __launch_bounds__(256)
void copy_out(const float* __restrict__ h, float* __restrict__ out, int n)
{
  int idx = blockIdx.x * 256 + threadIdx.x;
  if (idx < n) out[idx] = h[idx];
}

// ---------------------------------------------------------------------------
// MFMA GEMM:  C(M,N) = A(M,K) * Bt(N,K)^T,  A/Bt bf16, acc f32.
// 128x128 tile, BK=64, 4 waves (2x2), 64x64 per wave.
// LDS: linear 128B rows; global_load_lds width-16 with PRE-SWIZZLED source
// chunks (chunk ^= row&7); reads XOR-swizzle the byte offset. (m97+m173)
// ---------------------------------------------------------------------------
template<int EPI>
__global__ __launch_bounds__(256)
void gemm_bt(const ushort* __restrict__ A, const ushort* __restrict__ Bt,
             int M, int N, int K, const float* __restrict__ bias,
             float* __restrict__ resid, ushort* __restrict__ outbf)
{
  __shared__ ushort Asm[128 * 64];
  __shared__ ushort Bsm[128 * 64];
  const int bm = blockIdx.x, bn = blockIdx.y;
  const int tid = threadIdx.x;
  const int lane = tid & 63, w = tid >> 6;
  const int wm = w >> 1, wn = w & 1;
  const int c = lane & 15, g = lane >> 4;
  const size_t rowA0 = (size_t)bm * 128, rowB0 = (size_t)bn * 128;

  // staging geometry: wave w stages rows [w*32, w*32+32), 8 rows/instr.
  // lane: row += lane>>3, source chunk = (lane&7) ^ (lane>>3)  (pre-swizzle)
  const int sr  = lane >> 3;                  // 0..7
  const int sc8 = ((lane & 7) ^ sr) * 8;      // element offset in k-tile
  const ushort* aSrc = A  + (rowA0 + w * 32 + sr) * (size_t)K + sc8;
  const ushort* bSrc = Bt + (rowB0 + w * 32 + sr) * (size_t)K + sc8;
  const ushort* aDst = Asm + (w * 32) * 64;
  const ushort* bDst = Bsm + (w * 32) * 64;

  f32x4 acc[4][4] = {};

  for (int k0 = 0; k0 < K; k0 += 64) {
    __syncthreads();
    #pragma unroll
    for (int it = 0; it < 4; ++it) {
      __builtin_amdgcn_global_load_lds(AS1(aSrc + (size_t)(it * 8) * K + k0),
                                       AS3(aDst + it * 8 * 64), 16, 0, 0);
      __builtin_amdgcn_global_load_lds(AS1(bSrc + (size_t)(it * 8) * K + k0),
                                       AS3(bDst + it * 8 * 64), 16, 0, 0);
    }
    __syncthreads();   // compiler emits vmcnt(0) drain before barrier

    #pragma unroll
    for (int ks = 0; ks < 2; ++ks) {
      bf16x8 af[4], bfr[4];
      #pragma unroll
      for (int m = 0; m < 4; ++m) {
        int row = wm * 64 + m * 16 + c;
        af[m] = *(const bf16x8*)((const char*)Asm + row * 128 +
                                 ((ks * 64 + g * 16) ^ ((row & 7) << 4)));
      }
      #pragma unroll
      for (int n = 0; n < 4; ++n) {
        int row = wn * 64 + n * 16 + c;
        bfr[n] = *(const bf16x8*)((const char*)Bsm + row * 128 +
                                  ((ks * 64 + g * 16) ^ ((row & 7) << 4)));
      }
      #pragma unroll
      for (int m = 0; m < 4; ++m)
        #pragma unroll
        for (int n = 0; n < 4; ++n)
          acc[m][n] = __builtin_amdgcn_mfma_f32_16x16x32_bf16(
              af[m], bfr[n], acc[m][n], 0, 0, 0);
    }
  }

  const int cr = g * 4, cc = c;
  #pragma unroll
  for (int m = 0; m < 4; ++m) {
    #pragma unroll
    for (int n = 0; n < 4; ++n) {
      #pragma unroll
      for (int q = 0; q < 4; ++q) {
        size_t row = rowA0 + wm * 64 + m * 16 + cr + q;
        size_t col = rowB0 + wn * 64 + n * 16 + cc;
        float v = acc[m][n][q];
        if constexpr (EPI == 0) {
          outbf[row * N + col] = f2bf(v);
        } else if constexpr (EPI == 1) {
          float x = v + bias[col];
          float gl = 0.5f * x * (1.0f + erff(x * 0.70710678118654752f));
          outbf[row * N + col] = f2bf(gl);
        } else if constexpr (EPI == 2) {
          float x = v + bias[col] + resid[row * N + col];
          resid[row * N + col] = x;
          outbf[row * N + col] = f2bf(x);
        } else {
          float x = v + bias[col] + resid[row * N + col];
          resid[row * N + col] = x;
        }
      }
    }
  }
}

// ---------------------------------------------------------------------------
// pos MFMA GEMM: out[(b,h,i), r] = sum_d X[b,i,h*64+d] * posT[h, r, d]
// ---------------------------------------------------------------------------
__global__ __launch_bounds__(256)
void pos_mfma(const ushort* __restrict__ qkv,
              const ushort* __restrict__ posTq, const ushort* __restrict__ posTk,
              ushort* __restrict__ qpk, ushort* __restrict__ kpq)
{
  __shared__ ushort Asm[128 * 64];   // XOR-swizzled rows of 128B
  __shared__ ushort Bsm[128 * 64];
  const int bm = blockIdx.x, bn = blockIdx.y, z = blockIdx.z;
  const int h = z >> 1, which = z & 1;
  const ushort* A  = qkv + (which ? 768 : 0) + h * 64;
  const ushort* Bt = (which ? posTq : posTk) + (size_t)h * PTR_ * 64;
  ushort* out = which ? kpq : qpk;
  const int tid = threadIdx.x, lane = tid & 63, w = tid >> 6;
  const int wm = w >> 1, wn = w & 1;
  const int c = lane & 15, g = lane >> 4;

  #pragma unroll
  for (int it = 0; it < 4; ++it) {
    int row = (tid >> 3) + it * 32;
    int d0 = (tid & 7) * 8;
    uint4 av = *(const uint4*)(A + (size_t)(bm * 128 + row) * 2304 + d0);
    *(uint4*)((char*)Asm + row * 128 + ((d0 * 2) ^ ((row & 7) << 4))) = av;
    uint4 bv = *(const uint4*)(Bt + (size_t)(bn * 128 + row) * 64 + d0);
    *(uint4*)((char*)Bsm + row * 128 + ((d0 * 2) ^ ((row & 7) << 4))) = bv;
  }
  __syncthreads();

  f32x4 acc[4][4] = {};
  #pragma unroll
  for (int ks = 0; ks < 2; ++ks) {
    bf16x8 af[4], bfr[4];
    #pragma unroll
    for (int m = 0; m < 4; ++m) {
      int row = wm * 64 + m * 16 + c;
      af[m] = *(const bf16x8*)((const char*)Asm + row * 128 +
                               ((ks * 64 + g * 16) ^ ((row & 7) << 4)));
    }
    #pragma unroll
    for (int n = 0; n < 4; ++n) {
      int row = wn * 64 + n * 16 + c;
      bfr[n] = *(const bf16x8*)((const char*)Bsm + row * 128 +
                                ((ks * 64 + g * 16) ^ ((row & 7) << 4)));
    }
    #pragma unroll
    for (int m = 0; m < 4; ++m)
      #pragma unroll
      for (int n = 0; n < 4; ++n)
        acc[m][n] = __builtin_amdgcn_mfma_f32_16x16x32_bf16(
            af[m], bfr[n], acc[m][n], 0, 0, 0);
  }

  #pragma unroll
  for (int m = 0; m < 4; ++m) {
    #pragma unroll
    for (int n = 0; n < 4; ++n) {
      #pragma unroll
      for (int q = 0; q < 4; ++q) {
        int rowl = wm * 64 + m * 16 + g * 4 + q;
        int bi = bm * 128 + rowl;
        int b = bi >> 10, i = bi & 1023;
        int col = bn * 128 + wn * 64 + n * 16 + c;
        if (col < RP2_)
          out[((size_t)((b * H_ + h) * S_ + i)) * RP2_ + col] =
              f2bf(acc[m][n][q]);
      }
    }
  }
}

// ---------------------------------------------------------------------------
// Banded flash attention via MFMA.
// ---------------------------------------------------------------------------
__global__ __launch_bounds__(256)
void attn_mfma(const ushort* __restrict__ qkv,
               const ushort* __restrict__ qpk,  // (B*H*S, 272) bf16
               const ushort* __restrict__ kpq,
               ushort* __restrict__ ctx)        // (B*S, 768) bf16
{
  __shared__ ushort Qs[64 * 64];
  __shared__ ushort Ks[64 * 64];
  __shared__ ushort VTs[64 * 64];
  __shared__ ushort Ps[4][16 * 64];

  const int it0 = blockIdx.x;      // i-tile
  const int bh = blockIdx.y;
  const int b = bh / H_, h = bh - b * H_;
  const int i0 = it0 * 64;
  const int tid = threadIdx.x;
  const int lane = tid & 63, w = tid >> 6;
  const int c = lane & 15, g = lane >> 4;
  const size_t qkv_row0 = (size_t)(b * S_) * 2304;

  // stage Q (64 x 64), XOR-swizzled
  {
    int rr = tid >> 3, d0 = (tid & 7) * 8;
    #pragma unroll
    for (int it = 0; it < 2; ++it) {
      int row = rr + it * 32;
      uint4 v = *(const uint4*)(qkv + qkv_row0 + (size_t)(i0 + row) * 2304 +
                                h * 64 + d0);
      *(uint4*)((char*)Qs + row * 128 + ((d0 * 2) ^ ((row & 7) << 4))) = v;
    }
  }
  __syncthreads();

  // hoist Q B-fragments (col i = w*16 + c)
  bf16x8 qb[2];
  #pragma unroll
  for (int ks = 0; ks < 2; ++ks) {
    int row = w * 16 + c;
    qb[ks] = *(const bf16x8*)((const char*)Qs + row * 128 +
                              ((ks * 64 + g * 16) ^ ((row & 7) << 4)));
  }

  f32x4 acc[4] = {};
  float mrun = -1e30f, lrun = 0.f;
  const int i_mine = i0 + w * 16 + c;
  const ushort* qrow = qpk + ((size_t)(bh * S_) + i_mine) * RP2_;
  const ushort* kbase = kpq + (size_t)(bh * S_) * RP2_;

  for (int ccnk = 0; ccnk < 5; ++ccnk) {
    int jb = i0 - 128 + 64 * ccnk;
    if (jb < 0 || jb >= S_) continue;
    __syncthreads();
    // stage K chunk + transposed V chunk
    {
      int rr = tid >> 3, d0 = (tid & 7) * 8;
      #pragma unroll
      for (int it = 0; it < 2; ++it) {
        int row = rr + it * 32;
        const ushort* src = qkv + qkv_row0 + (size_t)(jb + row) * 2304 +
                            768 + h * 64 + d0;
        uint4 kv = *(const uint4*)src;
        *(uint4*)((char*)Ks + row * 128 + ((d0 * 2) ^ ((row & 7) << 4))) = kv;
        uint4 vv = *(const uint4*)(src + 768);
        ushort tmp[8];
        *(uint4*)tmp = vv;
        #pragma unroll
        for (int e = 0; e < 8; ++e) {
          int e2 = (e + tid) & 7;            // rotate to spread banks
          int d = d0 + e2;
          *(ushort*)((char*)VTs + d * 128 + ((row * 2) ^ ((d & 7) << 4))) =
              tmp[e2];
        }
      }
    }
    __syncthreads();

    // QK^T swapped: sc[f] holds S^T[j = 16f + 4g + q][i = w*16 + c]
    f32x4 sc[4];
    #pragma unroll
    for (int f = 0; f < 4; ++f) {
      f32x4 zz = {0.f, 0.f, 0.f, 0.f};
      #pragma unroll
      for (int ks = 0; ks < 2; ++ks) {
        int row = f * 16 + c;
        bf16x8 a = *(const bf16x8*)((const char*)Ks + row * 128 +
                                    ((ks * 64 + g * 16) ^ ((row & 7) << 4)));
        zz = __builtin_amdgcn_mfma_f32_16x16x32_bf16(a, qb[ks], zz, 0, 0, 0);
      }
      sc[f] = zz;
    }

    // bias + band mask
    float svals[16];
    #pragma unroll
    for (int f = 0; f < 4; ++f) {
      #pragma unroll
      for (int q = 0; q < 4; ++q) {
        int jl = f * 16 + g * 4 + q;
        int j = jb + jl;
        int dlt = j - i_mine;
        float s = sc[f][q];
        if (dlt >= -W_ && dlt <= W_) {
          s += bf2f(qrow[dlt + W_]);
          s += bf2f(kbase[(size_t)j * RP2_ + (W_ - dlt)]);
        } else {
          s = -1e30f;
        }
        svals[f * 4 + q] = s;
      }
    }

    // online softmax (per i: lanes c, c+16, c+32, c+48 share state)
    float cm = svals[0];
    #pragma unroll
    for (int q = 1; q < 16; ++q) cm = fmaxf(cm, svals[q]);
    cm = fmaxf(cm, __shfl_xor(cm, 16, 64));
    cm = fmaxf(cm, __shfl_xor(cm, 32, 64));
    float mnew = fmaxf(mrun, cm);
    float cf = __expf(mrun - mnew);
    float psum = 0.f;
    ushort pb[16];
    #pragma unroll
    for (int q = 0; q < 16; ++q) {
      float p = __expf(svals[q] - mnew);
      psum += p;
      pb[q] = f2bf(p);
    }
    psum += __shfl_xor(psum, 16, 64);
    psum += __shfl_xor(psum, 32, 64);
    lrun = lrun * cf + psum;
    mrun = mnew;

    // rescale ctx accumulator
    float cfr[4];
    #pragma unroll
    for (int q = 0; q < 4; ++q) cfr[q] = __shfl(cf, (g << 2) + q, 64);
    #pragma unroll
    for (int n = 0; n < 4; ++n)
      #pragma unroll
      for (int q = 0; q < 4; ++q) acc[n][q] *= cfr[q];

    // write P (bf16) to per-wave LDS in [i_local][jl] layout
    #pragma unroll
    for (int f = 0; f < 4; ++f) {
      uint2 p2;
      p2.x = (uint)pb[f * 4 + 0] | ((uint)pb[f * 4 + 1] << 16);
      p2.y = (uint)pb[f * 4 + 2] | ((uint)pb[f * 4 + 3] << 16);
      *(uint2*)((char*)&Ps[w][0] + c * 128 +
                ((f * 32 + g * 8) ^ ((c & 7) << 4))) = p2;
    }
    asm volatile("s_waitcnt lgkmcnt(0)" ::: "memory");

    // PV: acc[n] += P(16 x 64) * V(64 x d-frag n)
    #pragma unroll
    for (int ks = 0; ks < 2; ++ks) {
      bf16x8 pa = *(const bf16x8*)((const char*)&Ps[w][0] + c * 128 +
                                   ((ks * 64 + g * 16) ^ ((c & 7) << 4)));
      #pragma unroll
      for (int n = 0; n < 4; ++n) {
        int dd = n * 16 + c;
        bf16x8 bv = *(const bf16x8*)((const char*)VTs + dd * 128 +
                                     ((ks * 64 + g * 16) ^ ((dd & 7) << 4)));
        acc[n] = __builtin_amdgcn_mfma_f32_16x16x32_bf16(pa, bv, acc[n], 0, 0, 0);
      }
    }
  }

  // normalize + store ctx
  float inv = 1.0f / lrun;
  float invr[4];
  #pragma unroll
  for (int q = 0; q < 4; ++q) invr[q] = __shfl(inv, (g << 2) + q, 64);
  #pragma unroll
  for (int n = 0; n < 4; ++n) {
    #pragma unroll
    for (int q = 0; q < 4; ++q) {
      int i_g = i0 + w * 16 + g * 4 + q;
      int d = n * 16 + c;
      ctx[((size_t)(b * S_ + i_g)) * D_ + h * 64 + d] = f2bf(acc[n][q] * invr[q]);
    }
  }
}

// ---------------------------------------------------------------------------
// LayerNorm over D=768
// ---------------------------------------------------------------------------
__global__ __launch_bounds__(256)
void ln_kernel(float* __restrict__ h, ushort* __restrict__ hbf,
               const float* __restrict__ g, const float* __restrict__ be)
{
  __shared__ float red[8];
  __shared__ float mv[2];
  int row = blockIdx.x, tid = threadIdx.x;
  float* hr = h + (size_t)row * D_;
  float v0 = hr[tid], v1 = hr[tid + 256], v2 = hr[tid + 512];
  float s = v0 + v1 + v2;
  float s2 = v0 * v0 + v1 * v1 + v2 * v2;
  #pragma unroll
  for (int o = 32; o >= 1; o >>= 1) {
    s += __shfl_xor(s, o, 64);
    s2 += __shfl_xor(s2, o, 64);
  }
  int wave = tid >> 6, lane = tid & 63;
  if (lane == 0) { red[wave] = s; red[4 + wave] = s2; }
  __syncthreads();
  if (tid == 0) {
    float ts = red[0] + red[1] + red[2] + red[3];
    float t2 = red[4] + red[5] + red[6] + red[7];
    float mu = ts / (float)D_;
    float var = t2 / (float)D_ - mu * mu;
    mv[0] = mu; mv[1] = rsqrtf(var + 1e-8f);
  }
  __syncthreads();
  float mu = mv[0], rstd = mv[1];
  #pragma unroll
  for (int cidx = 0; cidx < 3; ++cidx) {
    int col = tid + cidx * 256;
    float v = (cidx == 0) ? v0 : (cidx == 1) ? v1 : v2;
    float x = (v - mu) * rstd * g[col] + be[col];
    hr[col] = x;
    hbf[(size_t)row * D_ + col] = f2bf(x);
  }
}

// ---------------------------------------------------------------------------
extern "C" void kernel_launch(void* const* d_in, const int* in_sizes, int n_in,
                              void* d_out, int out_size, void* d_ws, size_t ws_size,
                              hipStream_t stream)
{
  const float* hidden = (const float*)d_in[0];
  const float* wq  = (const float*)d_in[3];
  const float* wk  = (const float*)d_in[4];
  const float* wv  = (const float*)d_in[5];
  const float* pq  = (const float*)d_in[6];   // pos_q -> kpq
  const float* pk  = (const float*)d_in[7];   // pos_k -> qpk
  const float* wo  = (const float*)d_in[8];
  const float* bo  = (const float*)d_in[9];
  const float* w1  = (const float*)d_in[10];
  const float* b1  = (const float*)d_in[11];
  const float* w2  = (const float*)d_in[12];
  const float* b2  = (const float*)d_in[13];
  const float* lng = (const float*)d_in[14];
  const float* lnb = (const float*)d_in[15];
  float* out = (float*)d_out;

  char* ws = (char*)d_ws;
  size_t off = 0;
  auto alloc = [&](size_t bytes) {
    void* p = ws + off;
    off += (bytes + 255) & ~(size_t)255;
    return p;
  };
  const size_t NT = (size_t)B_ * S_;   // 4096 tokens
  ushort* wqkv_t = (ushort*)alloc((size_t)L_ * 2304 * 768 * 2);
  ushort* wo_t   = (ushort*)alloc((size_t)L_ * 768 * 768 * 2);
  ushort* w1_t   = (ushort*)alloc((size_t)L_ * 3072 * 768 * 2);
  ushort* w2_t   = (ushort*)alloc((size_t)L_ * 768 * 3072 * 2);
  ushort* posTq  = (ushort*)alloc((size_t)L_ * H_ * PTR_ * 64 * 2);
  ushort* posTk  = (ushort*)alloc((size_t)L_ * H_ * PTR_ * 64 * 2);
  float*  hbuf   = (float*) alloc(NT * D_ * 4);
  ushort* hbf    = (ushort*)alloc(NT * D_ * 2);
  ushort* qkv    = (ushort*)alloc(NT * 2304 * 2);
  ushort* qpk    = (ushort*)alloc((size_t)B_ * H_ * S_ * RP2_ * 2);
  ushort* kpq    = (ushort*)alloc((size_t)B_ * H_ * S_ * RP2_ * 2);
  ushort* ctx    = (ushort*)alloc(NT * D_ * 2);
  ushort* inter  = (ushort*)alloc(NT * F_ * 2);
  (void)ws_size; (void)in_sizes; (void)n_in; (void)out_size;

  // Weight transpose-convert (every call; inputs restored by harness)
  for (int l = 0; l < L_; ++l) {
    const size_t dd = (size_t)768 * 768;
    transpose_cvt<<<dim3(24, 24), 256, 0, stream>>>(
        wq + l * dd, wqkv_t + (size_t)l * 2304 * 768, 768, 768);
    transpose_cvt<<<dim3(24, 24), 256, 0, stream>>>(
        wk + l * dd, wqkv_t + (size_t)l * 2304 * 768 + dd, 768, 768);
    transpose_cvt<<<dim3(24, 24), 256, 0, stream>>>(
        wv + l * dd, wqkv_t + (size_t)l * 2304 * 768 + 2 * dd, 768, 768);
    transpose_cvt<<<dim3(24, 24), 256, 0, stream>>>(
        wo + l * dd, wo_t + l * dd, 768, 768);
    transpose_cvt<<<dim3(96, 24), 256, 0, stream>>>(
        w1 + (size_t)l * 768 * 3072, w1_t + (size_t)l * 3072 * 768, 768, 3072);
    transpose_cvt<<<dim3(24, 96), 256, 0, stream>>>(
        w2 + (size_t)l * 3072 * 768, w2_t + (size_t)l * 768 * 3072, 3072, 768);
  }
  pos_transpose<<<dim3(48, 12, 2), 256, 0, stream>>>(pq, posTq);
  pos_transpose<<<dim3(48, 12, 2), 256, 0, stream>>>(pk, posTk);

  init_h<<<(int)((NT * D_ + 255) / 256), 256, 0, stream>>>(
      hidden, hbuf, hbf, (int)(NT * D_));

  for (int l = 0; l < L_; ++l) {
    gemm_bt<0><<<dim3(32, 18), 256, 0, stream>>>(
        hbf, wqkv_t + (size_t)l * 2304 * 768, 4096, 2304, 768,
        nullptr, nullptr, qkv);
    pos_mfma<<<dim3(32, 3, 24), 256, 0, stream>>>(
        qkv, posTq + (size_t)l * H_ * PTR_ * 64,
        posTk + (size_t)l * H_ * PTR_ * 64, qpk, kpq);
    attn_mfma<<<dim3(16, 48), 256, 0, stream>>>(qkv, qpk, kpq, ctx);
    gemm_bt<2><<<dim3(32, 6), 256, 0, stream>>>(
        ctx, wo_t + (size_t)l * 768 * 768, 4096, 768, 768,
        bo + l * 768, hbuf, hbf);
    gemm_bt<1><<<dim3(32, 24), 256, 0, stream>>>(
        hbf, w1_t + (size_t)l * 3072 * 768, 4096, 3072, 768,
        b1 + l * 3072, nullptr, inter);
    gemm_bt<3><<<dim3(32, 6), 256, 0, stream>>>(
        inter, w2_t + (size_t)l * 768 * 3072, 4096, 768, 3072,
        b2 + l * 768, hbuf, nullptr);
    ln_kernel<<<4096, 256, 0, stream>>>(hbuf, hbf, lng + l * 768, lnb + l * 768);
  }

  copy_out<<<(int)((NT * D_ + 255) / 256), 256, 0, stream>>>(
      hbuf, out, (int)(NT * D_));
}